// Round 1
// baseline (47.781 us; speedup 1.0000x reference)
//
#include <hip/hip_runtime.h>

#define VOCAB 128000
#define HIST 512

// Vectorized full-array copy: out = in. float4 = 16 B/lane, coalesced.
__global__ void APPLY_PENALTY_5909874999394_copy(const float4* __restrict__ in,
                                                 float4* __restrict__ out,
                                                 long n4) {
    long i = (long)blockIdx.x * blockDim.x + threadIdx.x;
    long stride = (long)gridDim.x * blockDim.x;
    for (; i < n4; i += stride) {
        out[i] = in[i];
    }
}

// Scatter: for each row, last `pen_range` history ids get out[r,id] = logits[r,id] * p.
// Reads the ORIGINAL logits (not out), so duplicate ids write identical values.
__global__ void APPLY_PENALTY_5909874999394_scatter(const float* __restrict__ logits,
                                                    const int* __restrict__ save_id,
                                                    const float* __restrict__ pval,
                                                    const int* __restrict__ prange,
                                                    float* __restrict__ out) {
    int row = blockIdx.x;
    int pr = *prange;          // 64 at the reference shapes; read on-device (no host sync)
    float p = *pval;
    const int base = row * HIST + (HIST - pr);
    const long rowoff = (long)row * VOCAB;
    for (int k = threadIdx.x; k < pr; k += blockDim.x) {
        int idx = save_id[base + k];
        out[rowoff + idx] = logits[rowoff + idx] * p;
    }
}

extern "C" void kernel_launch(void* const* d_in, const int* in_sizes, int n_in,
                              void* d_out, int out_size, void* d_ws, size_t ws_size,
                              hipStream_t stream) {
    const float* logits  = (const float*)d_in[0];
    const int*   save_id = (const int*)d_in[1];
    const float* pval    = (const float*)d_in[2];
    const int*   prange  = (const int*)d_in[3];
    float* out = (float*)d_out;

    // out_size = B * VOCAB = 32,768,000; divisible by 4.
    long n4 = (long)out_size / 4;
    int block = 256;
    int grid = 2048;  // 256 CU x 8 blocks; grid-stride covers the rest
    APPLY_PENALTY_5909874999394_copy<<<grid, block, 0, stream>>>(
        (const float4*)logits, (float4*)out, n4);

    int rows = out_size / VOCAB;  // 256
    APPLY_PENALTY_5909874999394_scatter<<<rows, 64, 0, stream>>>(
        logits, save_id, pval, prange, out);
}

// Round 3
// 44.890 us; speedup vs baseline: 1.0644x; 1.0644x over previous
//
#include <hip/hip_runtime.h>

#define VOCAB 128000
#define HIST 512
#define ROW_F4 (VOCAB / 4)   // 32000 float4 per row

typedef float f32x4 __attribute__((ext_vector_type(4)));  // clang-native vector

// Fused: one block per row. Phase 1 copies the row (16B vector loads,
// nontemporal stores — out is write-once, keep it from evicting logits in
// L2/L3). __syncthreads() drains vmcnt(0) before the barrier (compiler
// semantics), so phase 2's penalty overwrites are ordered after the copy.
// Phase 2 reads ORIGINAL logits, so duplicate indices write identical values.
__global__ __launch_bounds__(1024)
void APPLY_PENALTY_5909874999394_fused(const f32x4* __restrict__ logits4,
                                       const float* __restrict__ logits,
                                       const int* __restrict__ save_id,
                                       const float* __restrict__ pval,
                                       const int* __restrict__ prange,
                                       f32x4* __restrict__ out4,
                                       float* __restrict__ out) {
    const int row = blockIdx.x;
    const long rowoff4 = (long)row * ROW_F4;

    // Phase 1: copy this row. 32000 / 1024 = 31.25 iters/thread, coalesced.
    for (int j = threadIdx.x; j < ROW_F4; j += blockDim.x) {
        f32x4 v = logits4[rowoff4 + j];
        __builtin_nontemporal_store(v, &out4[rowoff4 + j]);
    }

    __syncthreads();  // s_waitcnt vmcnt(0) before s_barrier — copy visible

    // Phase 2: apply penalties for this row (pr = 64 at reference shapes).
    const int pr = *prange;
    const float p = *pval;
    const int base = row * HIST + (HIST - pr);
    const long rowoff = (long)row * VOCAB;
    for (int k = threadIdx.x; k < pr; k += blockDim.x) {
        const int idx = save_id[base + k];
        out[rowoff + idx] = logits[rowoff + idx] * p;
    }
}

extern "C" void kernel_launch(void* const* d_in, const int* in_sizes, int n_in,
                              void* d_out, int out_size, void* d_ws, size_t ws_size,
                              hipStream_t stream) {
    const float* logits  = (const float*)d_in[0];
    const int*   save_id = (const int*)d_in[1];
    const float* pval    = (const float*)d_in[2];
    const int*   prange  = (const int*)d_in[3];
    float* out = (float*)d_out;

    const int rows = out_size / VOCAB;  // 256
    APPLY_PENALTY_5909874999394_fused<<<rows, 1024, 0, stream>>>(
        (const f32x4*)logits, logits, save_id, pval, prange,
        (f32x4*)out, out);
}